// Round 6
// baseline (616.596 us; speedup 1.0000x reference)
//
#include <hip/hip_runtime.h>

// ChannelKiller: out[b,c,s] = (c==0) ? x[b,c,s] : 0
// x: [16, 8, 1048576] fp32. Channel row = 4 MiB, batch = 32 MiB.
// R6: zeros via ONE pitched memset node (dst=out+4MiB, pitch=32MiB,
// width=28MiB, height=16) -> exactly channels 1..7, no double-write of
// channel 0, still on the rocclr fill path that beat my hand-written
// stores (R4: 107.7 vs R1-R3: 122). Then dense channel-0 copy (64 MiB r+w).
// Node count stays at 2 (R5 showed ~2 us/node replay overhead).

typedef float f32x4 __attribute__((ext_vector_type(4)));

#define S_LOG2 18   // float4 per channel row = 1048576/4 = 2^18

// One float4 per thread over channel-0 space: i in [0, 16*2^18).
// flat addr = (batch << 21) | within-row   (batch stride = 8*2^18 float4).
__global__ __launch_bounds__(256)
void ChannelKiller_copy_kernel(const f32x4* __restrict__ x,
                               f32x4* __restrict__ out) {
    int i = blockIdx.x * blockDim.x + threadIdx.x;
    int addr = ((i >> S_LOG2) << (S_LOG2 + 3)) | (i & ((1 << S_LOG2) - 1));
    out[addr] = x[addr];
}

extern "C" void kernel_launch(void* const* d_in, const int* in_sizes, int n_in,
                              void* d_out, int out_size, void* d_ws, size_t ws_size,
                              hipStream_t stream) {
    const f32x4* x = (const f32x4*)d_in[0];
    f32x4* out = (f32x4*)d_out;

    const size_t CHB = (size_t)1048576 * 4;  // 4 MiB channel row
    const size_t BATCHB = 8 * CHB;           // 32 MiB batch pitch

    // Phase 1: zero channels 1..7 of every batch in ONE pitched memset node.
    hipMemset2DAsync((char*)d_out + CHB, BATCHB, 0, 7 * CHB, 16, stream);

    // Phase 2: copy channel 0. 16 * 2^18 = 4194304 float4 = 16384 blocks x 256.
    ChannelKiller_copy_kernel<<<16384, 256, 0, stream>>>(x, out);
}

// Round 7
// 100.141 us; speedup vs baseline: 6.1573x; 6.1573x over previous
//
#include <hip/hip_runtime.h>

// ChannelKiller: out[b,c,s] = (c==0) ? x[b,c,s] : 0
// x: [16, 8, 1048576] fp32. Channel row = 2^18 float4, batch = 2^21 float4.
// R7: SINGLE dispatch, NO loops — exactly one float4 memory op per thread.
//   blocks [0, 114688):   zero channels 1..7  (470 MB pure store, no double-write)
//   blocks [114688, 131072): copy channel 0   (67 MB load + 67 MB store)
// Tests the hypothesis that loop-free one-op-per-thread stores match the
// rocclr fill path (~6.8 TB/s) that beat all my looped writers (~5.0 TB/s).

typedef float f32x4 __attribute__((ext_vector_type(4)));

#define S_LOG2 18            // float4 per channel row
#define ZBLK_PER_BATCH 7168  // 7*2^18/256 zero blocks per batch
#define NZB (16 * ZBLK_PER_BATCH)   // 114688 zero blocks
#define CBLK_PER_BATCH 1024  // 2^18/256 copy blocks per batch
#define NCB (16 * CBLK_PER_BATCH)   // 16384 copy blocks

__global__ __launch_bounds__(256)
void ChannelKiller_54365696033605_kernel(const f32x4* __restrict__ x,
                                         f32x4* __restrict__ out) {
    const int bid = blockIdx.x;
    const int tid = threadIdx.x;

    if (bid < NZB) {
        // zero: batch = bid/7168 (scalar, once), within-batch block index rem.
        int batch = bid / ZBLK_PER_BATCH;
        int rem = bid - batch * ZBLK_PER_BATCH;
        // addr covers channels 1..7: base (1<<18) + rem*256 + tid in [2^18, 2^21)
        int addr = (batch << (S_LOG2 + 3)) + (1 << S_LOG2) + (rem << 8) + tid;
        const f32x4 zf = {0.f, 0.f, 0.f, 0.f};
        out[addr] = zf;
    } else {
        int cid = bid - NZB;
        int batch = cid >> 10;             // 1024 copy blocks per batch
        int rem = cid & (CBLK_PER_BATCH - 1);
        int addr = (batch << (S_LOG2 + 3)) + (rem << 8) + tid;  // channel 0
        out[addr] = x[addr];
    }
}

extern "C" void kernel_launch(void* const* d_in, const int* in_sizes, int n_in,
                              void* d_out, int out_size, void* d_ws, size_t ws_size,
                              hipStream_t stream) {
    const f32x4* x = (const f32x4*)d_in[0];
    f32x4* out = (f32x4*)d_out;
    ChannelKiller_54365696033605_kernel<<<NZB + NCB, 256, 0, stream>>>(x, out);
}